// Round 3
// baseline (4805.032 us; speedup 1.0000x reference)
//
#include <hip/hip_runtime.h>
#include <hip/hip_bf16.h>
#include <cstdint>

typedef short short8 __attribute__((ext_vector_type(8)));
typedef float f32x4 __attribute__((ext_vector_type(4)));
typedef uint32_t u32x2 __attribute__((ext_vector_type(2)));
typedef unsigned short u16;

#define DEVINL __device__ __forceinline__

DEVINL u16 f32_to_bf16(float f) {
  uint32_t u = __builtin_bit_cast(uint32_t, f);
  u += 0x7FFFu + ((u >> 16) & 1u);   // RTNE; inputs are finite
  return (u16)(u >> 16);
}
DEVINL float bf16_to_f32(u16 b) {
  return __builtin_bit_cast(float, ((uint32_t)b) << 16);
}
DEVINL f32x4 mfma16(short8 a, short8 b, f32x4 c) {
  return __builtin_amdgcn_mfma_f32_16x16x32_bf16(a, b, c, 0, 0, 0);
}
// tanh(x) = 1 - 2/(1+e^{2x}); e^{2x} = exp2(x * 2*log2(e)). Inf-safe at both ends.
DEVINL float tanh_e2(float x) {
  float e = __builtin_amdgcn_exp2f(x * 2.88539008177793f);
  return 1.f - __fdividef(2.f, 1.f + e);
}

// ---------------- fp32 -> bf16 convert ----------------
__global__ void conv_bf16(const float* __restrict__ src, u16* __restrict__ dst, long n) {
  long i = ((long)blockIdx.x * blockDim.x + threadIdx.x) * 4;
  long stride = (long)gridDim.x * blockDim.x * 4;
  for (; i < n; i += stride) {
    float4 v = *(const float4*)(src + i);
    uint64_t p = (uint64_t)f32_to_bf16(v.x)
               | ((uint64_t)f32_to_bf16(v.y) << 16)
               | ((uint64_t)f32_to_bf16(v.z) << 32)
               | ((uint64_t)f32_to_bf16(v.w) << 48);
    *(uint64_t*)(dst + i) = p;
  }
}

__global__ void prep_bias(const float* __restrict__ bih, const float* __restrict__ bhh,
                          float* __restrict__ b1, float* __restrict__ b2) {
  int i = threadIdx.x;   // 512 threads
  b1[i] = bih[i]       + bhh[i];
  b2[i] = bih[512 + i] + bhh[512 + i];
}

// ---------------- GEMM: C[M,N] = A[M,K] @ B[N,K]^T + bias ----------------
// MODE 0: float out, [M][N] (FC head).
// MODE 1: bf16 out scattered into rec's U fragment layout (256-thread consumer):
//   (b,t,j): w=j>>7, tile=(j>>4)&7, q=(j>>2)&3, rg=j&3, tid = w*64+q*16+(b&15)
//   idx = ((t*8 + (b>>4))*256 + tid)*32 + (tile>>2)*16 + (tile&3)*4 + rg
template <int MODE>
__launch_bounds__(512, 2)
__global__ void gemm_bt(const u16* __restrict__ A, const u16* __restrict__ B,
                        const float* __restrict__ bias, void* __restrict__ out,
                        int M, int N, int K) {
  __shared__ u16 lA[128 * 64];
  __shared__ u16 lB[128 * 64];
  const int tid  = threadIdx.x;
  const int lane = tid & 63;
  const int wave = tid >> 6;
  const int wr = wave >> 2;
  const int wc = wave & 3;
  const int q   = lane >> 4;
  const int r16 = lane & 15;
  const int brow = blockIdx.x * 128;
  const int bcol = blockIdx.y * 128;

  f32x4 acc[4][2];
#pragma unroll
  for (int i = 0; i < 4; ++i)
#pragma unroll
    for (int j = 0; j < 2; ++j) acc[i][j] = (f32x4){0.f, 0.f, 0.f, 0.f};

  const int nkt = K >> 6;
  for (int kt = 0; kt < nkt; ++kt) {
#pragma unroll
    for (int s = 0; s < 2; ++s) {
      int c   = tid * 2 + s;
      int row = c >> 3;
      int cb  = (c & 7) * 16;
      int dsw = cb ^ ((row & 7) << 4);
      short8 va = *(const short8*)(A + (size_t)(brow + row) * K + kt * 64 + (cb >> 1));
      *(short8*)((char*)lA + row * 128 + dsw) = va;
      short8 vb = *(const short8*)(B + (size_t)(bcol + row) * K + kt * 64 + (cb >> 1));
      *(short8*)((char*)lB + row * 128 + dsw) = vb;
    }
    __syncthreads();
#pragma unroll
    for (int kk = 0; kk < 2; ++kk) {
      short8 af[4], bfr[2];
#pragma unroll
      for (int mt = 0; mt < 4; ++mt) {
        int row = wr * 64 + mt * 16 + r16;
        int byt = (kk * 64 + q * 16) ^ ((row & 7) << 4);
        af[mt] = *(const short8*)((const char*)lA + row * 128 + byt);
      }
#pragma unroll
      for (int nt = 0; nt < 2; ++nt) {
        int row = wc * 32 + nt * 16 + r16;
        int byt = (kk * 64 + q * 16) ^ ((row & 7) << 4);
        bfr[nt] = *(const short8*)((const char*)lB + row * 128 + byt);
      }
#pragma unroll
      for (int mt = 0; mt < 4; ++mt)
#pragma unroll
        for (int nt = 0; nt < 2; ++nt)
          acc[mt][nt] = mfma16(af[mt], bfr[nt], acc[mt][nt]);
    }
    __syncthreads();
  }

#pragma unroll
  for (int mt = 0; mt < 4; ++mt) {
#pragma unroll
    for (int nt = 0; nt < 2; ++nt) {
      int jc = bcol + wc * 32 + nt * 16 + r16;
      float bv = bias[jc];
      if (MODE == 0) {
#pragma unroll
        for (int rg = 0; rg < 4; ++rg) {
          int mg = brow + wr * 64 + mt * 16 + q * 4 + rg;
          ((float*)out)[(size_t)mg * N + jc] = acc[mt][nt][rg] + bv;
        }
      } else {
        int w2    = jc >> 7;
        int tile2 = (jc >> 4) & 7;
        int q2    = (jc >> 2) & 3;
        int rg2   = jc & 3;
        int colpart = (tile2 >> 2) * 16 + (tile2 & 3) * 4 + rg2;
#pragma unroll
        for (int rg = 0; rg < 4; ++rg) {
          int mg = brow + wr * 64 + mt * 16 + q * 4 + rg;
          int bb = mg >> 9;        // batch index (T=512)
          int t2 = mg & 511;       // time index
          int tid2 = w2 * 64 + q2 * 16 + (bb & 15);
          size_t idx = (((size_t)t2 * 8 + (bb >> 4)) * 256 + tid2) * 32 + colpart;
          ((u16*)out)[idx] = f32_to_bf16(acc[mt][nt][rg] + bv);
        }
      }
    }
  }
}

// ---------------- Recurrence: h_t = tanh(U_t + h_{t-1} @ Whh^T) ----------------
// 8 blocks (16 batch rows each), 4 waves (1/SIMD, 512-reg budget).
// Wave w owns j-cols [w*128, w*128+128): tiles 0..5 in registers (384 regs),
// tiles 6,7 in LDS (32 KiB/wave). h double-buffered in LDS, affine layout
// [kchunk][q][m][16B] -> single base VGPR + imm offsets, 2-way banks (free).
// Raw barrier (lgkmcnt only) -> global stores/loads never drained in-loop.
__launch_bounds__(256, 1)
__global__ void rnn_rec(const u16* __restrict__ Whh,
                        const u16* __restrict__ Ufrag,
                        u16* __restrict__ Hout,     // [128][512][512] bf16 (rows 125..127 = dump)
                        float* __restrict__ hidden) {
  __shared__ char LDS[163840];
  // [0,131072): W tiles: wave w at w*32768: [tt2][kk][q][r16][16B]
  // [131072,147456): h buf0   [147456,163840): h buf1, layout [kc][q'][m][16B]
  const int tid  = threadIdx.x;
  const int lane = tid & 63;
  const int w    = tid >> 6;
  const int q    = lane >> 4;
  const int r16  = lane & 15;
  const int g    = blockIdx.x;

  // ---- W register tiles 0..5 ----
  short8 wreg[6][16];
#pragma unroll
  for (int tt = 0; tt < 6; ++tt)
#pragma unroll
    for (int kk = 0; kk < 16; ++kk)
      wreg[tt][kk] = *(const short8*)(Whh + (size_t)(w * 128 + tt * 16 + r16) * 512 + kk * 32 + q * 8);

  // ---- W LDS tiles 6,7 ----
#pragma unroll
  for (int tt2 = 0; tt2 < 2; ++tt2)
#pragma unroll
    for (int kk = 0; kk < 16; ++kk) {
      short8 v = *(const short8*)(Whh + (size_t)(w * 128 + (6 + tt2) * 16 + r16) * 512 + kk * 32 + q * 8);
      *(short8*)(LDS + w * 32768 + tt2 * 16384 + kk * 1024 + q * 256 + r16 * 16) = v;
    }

  // ---- zero h buf0 ----
  {
    short8 z = {0, 0, 0, 0, 0, 0, 0, 0};
#pragma unroll
    for (int i = 0; i < 4; ++i)
      *(short8*)(LDS + 131072 + tid * 64 + i * 16) = z;
  }
  __syncthreads();

  // ---- bases ----
  const uint32_t hb_rd  = q * 256 + r16 * 16;
  const uint32_t rdA = 131072 + hb_rd, rdB = 147456 + hb_rd;
  const uint32_t hb_wrr = w * 4096 + (q >> 1) * 256 + r16 * 16 + (q & 1) * 8;
  const uint32_t wrA = 131072 + hb_wrr, wrB = 147456 + hb_wrr;
  const uint32_t wlb = w * 32768 + q * 256 + r16 * 16;
  const uint32_t uvoff = (uint32_t)(g * 256 + tid) * 64;   // bytes
  const int    jb = w * 128 + q * 4;
  const size_t hout_thr = (size_t)(g * 16 + r16) * 262144 + jb;  // b up to 127: dump rows

  const char* Ub = (const char*)Ufrag;
  short8 u0 = *(const short8*)(Ub + uvoff);
  short8 u1 = *(const short8*)(Ub + uvoff + 16);

#define DINIT(Da, Db, ua, ub) { \
    _Pragma("unroll") for (int rg = 0; rg < 4; ++rg) { \
      Da[rg] = bf16_to_f32((u16)ua[rg]); Db[rg] = bf16_to_f32((u16)ua[rg + 4]); } \
    _Pragma("unroll") for (int rg = 0; rg < 4; ++rg) { \
      (void)0; } \
  }

#define EPI_TILE(Dt, tile, WRX, HT) { \
    float e0 = tanh_e2(Dt[0]), e1 = tanh_e2(Dt[1]); \
    float e2 = tanh_e2(Dt[2]), e3 = tanh_e2(Dt[3]); \
    uint32_t lo = (uint32_t)f32_to_bf16(e0) | ((uint32_t)f32_to_bf16(e1) << 16); \
    uint32_t hi = (uint32_t)f32_to_bf16(e2) | ((uint32_t)f32_to_bf16(e3) << 16); \
    u32x2 pk; pk[0] = lo; pk[1] = hi; \
    *(u32x2*)(LDS + (WRX) + ((tile) >> 1) * 1024 + ((tile) & 1) * 512) = pk; \
    *(u32x2*)((HT) + (tile) * 16) = pk; \
  }

#define BODY(T_, RDX, WRX, UT, UTN) { \
    f32x4 D0, D1, D2, D3, D4, D5, D6, D7; \
    _Pragma("unroll") for (int rg = 0; rg < 4; ++rg) { \
      D0[rg] = bf16_to_f32((u16)u0[rg]); D1[rg] = bf16_to_f32((u16)u0[rg + 4]); \
      D2[rg] = bf16_to_f32((u16)u1[rg]); D3[rg] = bf16_to_f32((u16)u1[rg + 4]); } \
    u0 = *(const short8*)((UT) + uvoff + 32); \
    u1 = *(const short8*)((UT) + uvoff + 48); \
    _Pragma("unroll") for (int kk = 0; kk < 16; ++kk) { \
      short8 hf = *(const short8*)(LDS + (RDX) + kk * 1024); \
      D0 = mfma16(wreg[0][kk], hf, D0); \
      D1 = mfma16(wreg[1][kk], hf, D1); \
      D2 = mfma16(wreg[2][kk], hf, D2); \
      D3 = mfma16(wreg[3][kk], hf, D3); } \
    _Pragma("unroll") for (int rg = 0; rg < 4; ++rg) { \
      D4[rg] = bf16_to_f32((u16)u0[rg]); D5[rg] = bf16_to_f32((u16)u0[rg + 4]); \
      D6[rg] = bf16_to_f32((u16)u1[rg]); D7[rg] = bf16_to_f32((u16)u1[rg + 4]); } \
    u0 = *(const short8*)((UTN) + uvoff); \
    u1 = *(const short8*)((UTN) + uvoff + 16); \
    _Pragma("unroll") for (int kk = 0; kk < 16; ++kk) { \
      short8 hf  = *(const short8*)(LDS + (RDX) + kk * 1024); \
      short8 wl0 = *(const short8*)(LDS + wlb + kk * 1024); \
      short8 wl1 = *(const short8*)(LDS + wlb + 16384 + kk * 1024); \
      D4 = mfma16(wreg[4][kk], hf, D4); \
      D5 = mfma16(wreg[5][kk], hf, D5); \
      D6 = mfma16(wl0, hf, D6); \
      D7 = mfma16(wl1, hf, D7); } \
    u16* HT = Hout + (size_t)(T_) * 512 + hout_thr; \
    EPI_TILE(D0, 0, WRX, HT); EPI_TILE(D1, 1, WRX, HT); \
    EPI_TILE(D2, 2, WRX, HT); EPI_TILE(D3, 3, WRX, HT); \
    EPI_TILE(D4, 4, WRX, HT); EPI_TILE(D5, 5, WRX, HT); \
    EPI_TILE(D6, 6, WRX, HT); EPI_TILE(D7, 7, WRX, HT); \
    asm volatile("s_waitcnt lgkmcnt(0)" ::: "memory"); \
    __builtin_amdgcn_s_barrier(); \
    asm volatile("" ::: "memory"); \
  }

  for (int t = 0; t < 512; t += 2) {
    const char* UT0 = Ub + (size_t)t * 131072;
    BODY(t,     rdA, wrB, UT0,          UT0 + 131072);
    BODY(t + 1, rdB, wrA, UT0 + 131072, UT0 + 262144);
  }

  // ---- final hidden state: read back own h(T) slots from buf0 ----
  {
    int b = g * 16 + r16;
    if (b < 125) {
#pragma unroll
      for (int tile = 0; tile < 8; ++tile) {
        u32x2 pk = *(const u32x2*)(LDS + wrA + (tile >> 1) * 1024 + (tile & 1) * 512);
        float4 v;
        v.x = __builtin_bit_cast(float, pk[0] << 16);
        v.y = __builtin_bit_cast(float, pk[0] & 0xFFFF0000u);
        v.z = __builtin_bit_cast(float, pk[1] << 16);
        v.w = __builtin_bit_cast(float, pk[1] & 0xFFFF0000u);
        *(float4*)(hidden + (size_t)b * 512 + jb + tile * 16) = v;
      }
    }
  }
#undef BODY
#undef EPI_TILE
#undef DINIT
}

extern "C" void kernel_launch(void* const* d_in, const int* in_sizes, int n_in,
                              void* d_out, int out_size, void* d_ws, size_t ws_size,
                              hipStream_t stream) {
  const float* x   = (const float*)d_in[0];
  const float* wih = (const float*)d_in[1];   // [2,512,512]
  const float* whh = (const float*)d_in[2];   // [2,512,512]
  const float* bih = (const float*)d_in[3];   // [2,512]
  const float* bhh = (const float*)d_in[4];   // [2,512]
  const float* fcw = (const float*)d_in[5];   // [1024,512]
  const float* fcb = (const float*)d_in[6];   // [1024]

  // workspace layout
  char* ws = (char*)d_ws;
  u16* Xb    = (u16*)ws;                          // 65,536,000 B
  u16* Hb    = (u16*)(ws + 65536000);             // 67,108,864 B ([128][512][512])
  u16* Wih1  = (u16*)(ws + 132644864);            // 524,288 B each
  u16* Whh1  = Wih1 + 262144;
  u16* Wih2  = Whh1 + 262144;
  u16* Whh2  = Wih2 + 262144;
  u16* FCW   = Whh2 + 262144;                     // 1 MB
  float* b1  = (float*)(FCW + 524288);
  float* b2  = b1 + 512;

  // U scratch (fragment layout, 64 MB) lives in d_out; dead before FC writes
  u16*   Ubf  = (u16*)d_out;
  float* outp = (float*)d_out;
  float* hid  = outp + 65536000;                  // [2][125][512]

  conv_bf16<<<2048, 256, 0, stream>>>(x, Xb, 32768000L);
  conv_bf16<<<256, 256, 0, stream>>>(wih,          Wih1, 262144L);
  conv_bf16<<<256, 256, 0, stream>>>(wih + 262144, Wih2, 262144L);
  conv_bf16<<<256, 256, 0, stream>>>(whh,          Whh1, 262144L);
  conv_bf16<<<256, 256, 0, stream>>>(whh + 262144, Whh2, 262144L);
  conv_bf16<<<512, 256, 0, stream>>>(fcw, FCW, 524288L);
  prep_bias<<<1, 512, 0, stream>>>(bih, bhh, b1, b2);

  dim3 blk(512);
  dim3 g1(500, 4);   // 64000/128 x 512/128
  dim3 g2(500, 8);   // 64000/128 x 1024/128

  // layer 1
  gemm_bt<1><<<g1, blk, 0, stream>>>(Xb, Wih1, b1, Ubf, 64000, 512, 512);
  rnn_rec<<<8, 256, 0, stream>>>(Whh1, Ubf, Hb, hid);
  // layer 2
  gemm_bt<1><<<g1, blk, 0, stream>>>(Hb, Wih2, b2, Ubf, 64000, 512, 512);
  rnn_rec<<<8, 256, 0, stream>>>(Whh2, Ubf, Hb, hid + 64000);
  // FC head
  gemm_bt<0><<<g2, blk, 0, stream>>>(Hb, FCW, fcb, d_out, 64000, 1024, 512);

  (void)in_sizes; (void)n_in; (void)out_size; (void)ws_size;
}

// Round 4
// 2605.455 us; speedup vs baseline: 1.8442x; 1.8442x over previous
//
#include <hip/hip_runtime.h>
#include <hip/hip_bf16.h>
#include <cstdint>

typedef short short8 __attribute__((ext_vector_type(8)));
typedef float f32x4 __attribute__((ext_vector_type(4)));
typedef uint32_t u32x2 __attribute__((ext_vector_type(2)));
typedef unsigned short u16;

#define DEVINL __device__ __forceinline__

DEVINL u16 f32_to_bf16(float f) {
  uint32_t u = __builtin_bit_cast(uint32_t, f);
  u += 0x7FFFu + ((u >> 16) & 1u);   // RTNE; inputs are finite
  return (u16)(u >> 16);
}
DEVINL float bf16_to_f32(u16 b) {
  return __builtin_bit_cast(float, ((uint32_t)b) << 16);
}
DEVINL f32x4 mfma16(short8 a, short8 b, f32x4 c) {
  return __builtin_amdgcn_mfma_f32_16x16x32_bf16(a, b, c, 0, 0, 0);
}
// tanh(x) = 1 - 2/(1+e^{2x}); e^{2x} = exp2(x * 2*log2(e)). Inf-safe at both ends.
DEVINL float tanh_e2(float x) {
  float e = __builtin_amdgcn_exp2f(x * 2.88539008177793f);
  return 1.f - __fdividef(2.f, 1.f + e);
}

// ---------------- fp32 -> bf16 convert ----------------
__global__ void conv_bf16(const float* __restrict__ src, u16* __restrict__ dst, long n) {
  long i = ((long)blockIdx.x * blockDim.x + threadIdx.x) * 4;
  long stride = (long)gridDim.x * blockDim.x * 4;
  for (; i < n; i += stride) {
    float4 v = *(const float4*)(src + i);
    uint64_t p = (uint64_t)f32_to_bf16(v.x)
               | ((uint64_t)f32_to_bf16(v.y) << 16)
               | ((uint64_t)f32_to_bf16(v.z) << 32)
               | ((uint64_t)f32_to_bf16(v.w) << 48);
    *(uint64_t*)(dst + i) = p;
  }
}

__global__ void prep_bias(const float* __restrict__ bih, const float* __restrict__ bhh,
                          float* __restrict__ b1, float* __restrict__ b2) {
  int i = threadIdx.x;   // 512 threads
  b1[i] = bih[i]       + bhh[i];
  b2[i] = bih[512 + i] + bhh[512 + i];
}

// ---------------- GEMM: C[M,N] = A[M,K] @ B[N,K]^T + bias ----------------
// MODE 0: float out, [M][N] (FC head).
// MODE 1: bf16 out scattered into rec's U fragment layout (512-thread consumer):
//   (b,t,j): tid = (j>>6)*64 + ((j>>2)&3)*16 + (b&15)
//   idx = ((t*8 + (b>>4))*512 + tid)*16 + ((j>>4)&3)*4 + (j&3)
template <int MODE>
__launch_bounds__(512, 2)
__global__ void gemm_bt(const u16* __restrict__ A, const u16* __restrict__ B,
                        const float* __restrict__ bias, void* __restrict__ out,
                        int M, int N, int K) {
  __shared__ u16 lA[128 * 64];
  __shared__ u16 lB[128 * 64];
  const int tid  = threadIdx.x;
  const int lane = tid & 63;
  const int wave = tid >> 6;
  const int wr = wave >> 2;
  const int wc = wave & 3;
  const int q   = lane >> 4;
  const int r16 = lane & 15;
  const int brow = blockIdx.x * 128;
  const int bcol = blockIdx.y * 128;

  f32x4 acc[4][2];
#pragma unroll
  for (int i = 0; i < 4; ++i)
#pragma unroll
    for (int j = 0; j < 2; ++j) acc[i][j] = (f32x4){0.f, 0.f, 0.f, 0.f};

  const int nkt = K >> 6;
  for (int kt = 0; kt < nkt; ++kt) {
#pragma unroll
    for (int s = 0; s < 2; ++s) {
      int c   = tid * 2 + s;
      int row = c >> 3;
      int cb  = (c & 7) * 16;
      int dsw = cb ^ ((row & 7) << 4);
      short8 va = *(const short8*)(A + (size_t)(brow + row) * K + kt * 64 + (cb >> 1));
      *(short8*)((char*)lA + row * 128 + dsw) = va;
      short8 vb = *(const short8*)(B + (size_t)(bcol + row) * K + kt * 64 + (cb >> 1));
      *(short8*)((char*)lB + row * 128 + dsw) = vb;
    }
    __syncthreads();
#pragma unroll
    for (int kk = 0; kk < 2; ++kk) {
      short8 af[4], bfr[2];
#pragma unroll
      for (int mt = 0; mt < 4; ++mt) {
        int row = wr * 64 + mt * 16 + r16;
        int byt = (kk * 64 + q * 16) ^ ((row & 7) << 4);
        af[mt] = *(const short8*)((const char*)lA + row * 128 + byt);
      }
#pragma unroll
      for (int nt = 0; nt < 2; ++nt) {
        int row = wc * 32 + nt * 16 + r16;
        int byt = (kk * 64 + q * 16) ^ ((row & 7) << 4);
        bfr[nt] = *(const short8*)((const char*)lB + row * 128 + byt);
      }
#pragma unroll
      for (int mt = 0; mt < 4; ++mt)
#pragma unroll
        for (int nt = 0; nt < 2; ++nt)
          acc[mt][nt] = mfma16(af[mt], bfr[nt], acc[mt][nt]);
    }
    __syncthreads();
  }

#pragma unroll
  for (int mt = 0; mt < 4; ++mt) {
#pragma unroll
    for (int nt = 0; nt < 2; ++nt) {
      int jc = bcol + wc * 32 + nt * 16 + r16;
      float bv = bias[jc];
      if (MODE == 0) {
#pragma unroll
        for (int rg = 0; rg < 4; ++rg) {
          int mg = brow + wr * 64 + mt * 16 + q * 4 + rg;
          ((float*)out)[(size_t)mg * N + jc] = acc[mt][nt][rg] + bv;
        }
      } else {
        int tidc    = (jc >> 6) * 64 + ((jc >> 2) & 3) * 16;   // + (bb&15)
        int colpart = ((jc >> 4) & 3) * 4 + (jc & 3);
#pragma unroll
        for (int rg = 0; rg < 4; ++rg) {
          int mg = brow + wr * 64 + mt * 16 + q * 4 + rg;
          int bb = mg >> 9;        // batch index (T=512)
          int t2 = mg & 511;       // time index
          size_t idx = (((size_t)t2 * 8 + (bb >> 4)) * 512 + tidc + (bb & 15)) * 16 + colpart;
          ((u16*)out)[idx] = f32_to_bf16(acc[mt][nt][rg] + bv);
        }
      }
    }
  }
}

// ---------------- Recurrence: h_t = tanh(U_t + h_{t-1} @ Whh^T) ----------------
// 8 blocks (16 batch rows each), 8 waves, EXACTLY 2 waves/SIMD (256-reg budget).
// Wave w owns j-cols [w*64, w*64+64): tiles 0..2 in regs (192), tile 3 in LDS.
// LDS: W 128 KiB (8 x 16 KiB, [kk][q][r16][16B]) + h dbuf 32 KiB (same layout).
// Single merged kk loop: 16 hf + 16 wl reads, 64 MFMA per wave per step.
// Raw barrier (lgkmcnt only): global U-loads / H-stores never drained in-loop.
__attribute__((amdgpu_flat_work_group_size(512, 512), amdgpu_waves_per_eu(2, 2)))
__global__ void rnn_rec(const u16* __restrict__ Whh,
                        const u16* __restrict__ Ufrag,
                        u16* __restrict__ Hout,     // [128][512][512] bf16 (rows 125..127 dump)
                        float* __restrict__ hidden) {
  __shared__ char LDS[163840];
  // [0,131072): W LDS tiles, wave w at w*16384, addr = kk*1024 + q*256 + r16*16
  // [131072,147456): h buf0   [147456,163840): h buf1, layout [kk][q][m(r16)][16B]
  const int tid  = threadIdx.x;
  const int lane = tid & 63;
  const int w    = tid >> 6;          // 0..7
  const int q    = lane >> 4;
  const int r16  = lane & 15;
  const int g    = blockIdx.x;

  // ---- W register tiles 0..2 (j = w*64 + tt*16 + r16) ----
  short8 wreg[3][16];
#pragma unroll
  for (int tt = 0; tt < 3; ++tt)
#pragma unroll
    for (int kk = 0; kk < 16; ++kk)
      wreg[tt][kk] = *(const short8*)(Whh + (size_t)(w * 64 + tt * 16 + r16) * 512 + kk * 32 + q * 8);

  // ---- W LDS tile 3 (j = w*64 + 48 + r16) ----
#pragma unroll
  for (int kk = 0; kk < 16; ++kk) {
    short8 v = *(const short8*)(Whh + (size_t)(w * 64 + 48 + r16) * 512 + kk * 32 + q * 8);
    *(short8*)(LDS + w * 16384 + kk * 1024 + q * 256 + r16 * 16) = v;
  }

  // ---- zero h buf0 ----
  {
    short8 z = {0, 0, 0, 0, 0, 0, 0, 0};
    *(short8*)(LDS + 131072 + tid * 32)      = z;
    *(short8*)(LDS + 131072 + tid * 32 + 16) = z;
  }
  __syncthreads();

  // ---- loop-invariant bases ----
  uint32_t rd = 131072 + q * 256 + r16 * 16;                 // h read base (buf0)
  // h write: thread covers j = w*64 + tt*16 + q*4 + {0..3} -> [kk=(j>>5)][(j>>3)&3][r16][(j&7)*2]
  uint32_t wr = 147456 + w * 2048 + (q >> 1) * 256 + r16 * 16 + (q & 1) * 8;  // (buf1) + imm per tile
  const uint32_t wlb = w * 16384 + q * 256 + r16 * 16;       // W LDS base
  const int jb = w * 64 + q * 4;
  const char* uptr = (const char*)Ufrag + (size_t)(g * 512 + tid) * 32;
  u16* hptr = Hout + (size_t)(g * 16 + r16) * 262144 + jb;   // += 512 elems/step

  short8 u0 = *(const short8*)(uptr);
  short8 u1 = *(const short8*)(uptr + 16);
  uptr += 131072;

  for (int t = 0; t < 512; ++t) {
    // D init from current U (slot tt*4+rg; u0 = tiles 0,1; u1 = tiles 2,3)
    f32x4 D0, D1, D2, D3;
#pragma unroll
    for (int rg = 0; rg < 4; ++rg) {
      D0[rg] = bf16_to_f32((u16)u0[rg]);
      D1[rg] = bf16_to_f32((u16)u0[rg + 4]);
      D2[rg] = bf16_to_f32((u16)u1[rg]);
      D3[rg] = bf16_to_f32((u16)u1[rg + 4]);
    }
    // prefetch next step's U (full body to hide HBM latency)
    short8 n0 = *(const short8*)(uptr);
    short8 n1 = *(const short8*)(uptr + 16);
    uptr += 131072;

    // merged kk loop: 1 hf + 1 wl read, 4 MFMAs
#pragma unroll
    for (int kk = 0; kk < 16; ++kk) {
      short8 hf = *(const short8*)(LDS + rd + kk * 1024);
      short8 wl = *(const short8*)(LDS + wlb + kk * 1024);
      D0 = mfma16(wreg[0][kk], hf, D0);
      D1 = mfma16(wreg[1][kk], hf, D1);
      D2 = mfma16(wreg[2][kk], hf, D2);
      D3 = mfma16(wl, hf, D3);
    }

    // epilogue: tanh -> pack -> LDS h(next) + global H
#define EPI_TILE(Dt, tt) { \
    float e0 = tanh_e2(Dt[0]), e1 = tanh_e2(Dt[1]); \
    float e2 = tanh_e2(Dt[2]), e3 = tanh_e2(Dt[3]); \
    uint32_t lo = (uint32_t)f32_to_bf16(e0) | ((uint32_t)f32_to_bf16(e1) << 16); \
    uint32_t hi = (uint32_t)f32_to_bf16(e2) | ((uint32_t)f32_to_bf16(e3) << 16); \
    u32x2 pk; pk[0] = lo; pk[1] = hi; \
    *(u32x2*)(LDS + wr + ((tt) >> 1) * 1024 + ((tt) & 1) * 512) = pk; \
    *(u32x2*)(hptr + (tt) * 16) = pk; \
  }
    EPI_TILE(D0, 0); EPI_TILE(D1, 1); EPI_TILE(D2, 2); EPI_TILE(D3, 3);
#undef EPI_TILE
    hptr += 512;
    u0 = n0; u1 = n1;
    rd ^= 16384; wr ^= 16384;   // swap h buffers

    asm volatile("s_waitcnt lgkmcnt(0)" ::: "memory");
    __builtin_amdgcn_s_barrier();
    asm volatile("" ::: "memory");
  }

  // ---- final hidden state: h(T-1) is in buf0 (t=511 wrote buf0); read own slots ----
  {
    int b = g * 16 + r16;
    if (b < 125) {
      uint32_t fwr = 131072 + w * 2048 + (q >> 1) * 256 + r16 * 16 + (q & 1) * 8;
#pragma unroll
      for (int tt = 0; tt < 4; ++tt) {
        u32x2 pk = *(const u32x2*)(LDS + fwr + (tt >> 1) * 1024 + (tt & 1) * 512);
        float4 v;
        v.x = __builtin_bit_cast(float, pk[0] << 16);
        v.y = __builtin_bit_cast(float, pk[0] & 0xFFFF0000u);
        v.z = __builtin_bit_cast(float, pk[1] << 16);
        v.w = __builtin_bit_cast(float, pk[1] & 0xFFFF0000u);
        *(float4*)(hidden + (size_t)b * 512 + jb + tt * 16) = v;
      }
    }
  }
}

extern "C" void kernel_launch(void* const* d_in, const int* in_sizes, int n_in,
                              void* d_out, int out_size, void* d_ws, size_t ws_size,
                              hipStream_t stream) {
  const float* x   = (const float*)d_in[0];
  const float* wih = (const float*)d_in[1];   // [2,512,512]
  const float* whh = (const float*)d_in[2];   // [2,512,512]
  const float* bih = (const float*)d_in[3];   // [2,512]
  const float* bhh = (const float*)d_in[4];   // [2,512]
  const float* fcw = (const float*)d_in[5];   // [1024,512]
  const float* fcb = (const float*)d_in[6];   // [1024]

  // workspace layout
  char* ws = (char*)d_ws;
  u16* Xb    = (u16*)ws;                          // 65,536,000 B
  u16* Hb    = (u16*)(ws + 65536000);             // 67,108,864 B ([128][512][512])
  u16* Wih1  = (u16*)(ws + 132644864);            // 524,288 B each
  u16* Whh1  = Wih1 + 262144;
  u16* Wih2  = Whh1 + 262144;
  u16* Whh2  = Wih2 + 262144;
  u16* FCW   = Whh2 + 262144;                     // 1 MB
  float* b1  = (float*)(FCW + 524288);
  float* b2  = b1 + 512;

  // U scratch (fragment layout, 64 MB) lives in d_out; dead before FC writes
  u16*   Ubf  = (u16*)d_out;
  float* outp = (float*)d_out;
  float* hid  = outp + 65536000;                  // [2][125][512]

  conv_bf16<<<2048, 256, 0, stream>>>(x, Xb, 32768000L);
  conv_bf16<<<256, 256, 0, stream>>>(wih,          Wih1, 262144L);
  conv_bf16<<<256, 256, 0, stream>>>(wih + 262144, Wih2, 262144L);
  conv_bf16<<<256, 256, 0, stream>>>(whh,          Whh1, 262144L);
  conv_bf16<<<256, 256, 0, stream>>>(whh + 262144, Whh2, 262144L);
  conv_bf16<<<512, 256, 0, stream>>>(fcw, FCW, 524288L);
  prep_bias<<<1, 512, 0, stream>>>(bih, bhh, b1, b2);

  dim3 blk(512);
  dim3 g1(500, 4);   // 64000/128 x 512/128
  dim3 g2(500, 8);   // 64000/128 x 1024/128

  // layer 1
  gemm_bt<1><<<g1, blk, 0, stream>>>(Xb, Wih1, b1, Ubf, 64000, 512, 512);
  rnn_rec<<<8, 512, 0, stream>>>(Whh1, Ubf, Hb, hid);
  // layer 2
  gemm_bt<1><<<g1, blk, 0, stream>>>(Hb, Wih2, b2, Ubf, 64000, 512, 512);
  rnn_rec<<<8, 512, 0, stream>>>(Whh2, Ubf, Hb, hid + 64000);
  // FC head
  gemm_bt<0><<<g2, blk, 0, stream>>>(Hb, FCW, fcb, d_out, 64000, 1024, 512);

  (void)in_sizes; (void)n_in; (void)out_size; (void)ws_size;
}